// Round 1
// baseline (37406.873 us; speedup 1.0000x reference)
//
#include <hip/hip_runtime.h>

// Problem constants (B,T,D fixed by setup_inputs)
#define BB_ 16
#define TT_ 2048
#define DD_ 1024
#define GG_ 4096   // 4*D
#define NWG 256
#define NT  256
#define SCOPE_AGENT __HIP_MEMORY_SCOPE_AGENT

// Persistent-LSTM, round 4: batch-split 2-stage software pipeline.
//  - Batches split into group A (0-7) and group B (8-15): independent recurrences.
//  - Phase X(t): commit gathered h/x regs -> LDS; deferred flag publish (drain merges
//    with entry wait); x-matvec; all-wave spin; ISSUE gather+x-prefetch for the
//    OTHER group (lands under h-matvec+reduce of this phase); h-matvec; pointwise.
//  - hbuf double-buffered per group; flags are monotonic step counters per group.
//    Spin transitively guarantees all gathers of buf[p] complete >1 step before
//    buf[p] is overwritten.
//  - Weights register-resident (128 VGPRs of float4); arithmetic order identical to
//    round 3 -> bitwise-identical results.

__device__ __forceinline__ void fma4(float4& a, float s, const float4& w) {
  a.x = fmaf(s, w.x, a.x);
  a.y = fmaf(s, w.y, a.y);
  a.z = fmaf(s, w.z, a.z);
  a.w = fmaf(s, w.w, a.w);
}

__device__ __forceinline__ float sigm_f(float v) { return 1.f / (1.f + __expf(-v)); }
__device__ __forceinline__ float tanh_f(float v) { return 1.f - 2.f / (1.f + __expf(2.f * v)); }

// hbuf layout (floats): [A0 @0][A1 @8192][B0 @16384][B1 @24576]
// flags layout (uints): [flags_A @0][flags_B @NWG]
// flag value v = t+1+G published at phase G(t) start covers h of the PREVIOUS phase:
//   A(t) publishes flags_B = t+1  (h_B(t-1); t=0 covers the h0 prefill)
//   B(t) publishes flags_A = t+2  (h_A(t))

template <int G>
__device__ __forceinline__ void run_phase(
    int t, int wgid, int tid, int w, int lane,
    const float4 (&wi_r)[16], const float4 (&wh_r)[16],
    float* sh_h, float* sh_x, float* sh_part, float (*sh_yg)[16], float* sh_bias,
    const float* __restrict__ x, float* __restrict__ out, float* __restrict__ carry_out,
    float* __restrict__ hbuf, unsigned* __restrict__ flags,
    float& c_state,
    unsigned long long (&hreg_in)[16], float4 (&xreg_in)[8],
    unsigned long long (&hreg_out)[16], float4 (&xreg_out)[8])
{
  const int RB = G * 8;   // batch-row base of this phase's group

  // ---- entry: commit gathered h + prefetched x into LDS (skip only at A(0): prologue) ----
  if (G == 1 || t > 0) {
    unsigned long long* sh8 = (unsigned long long*)sh_h + RB * (DD_ / 2);
#pragma unroll
    for (int r = 0; r < 16; ++r) sh8[r * NT + tid] = hreg_in[r];
    float4* sx4 = (float4*)sh_x + RB * (DD_ / 4);
#pragma unroll
    for (int r = 0; r < 8; ++r) sx4[r * NT + tid] = xreg_in[r];
  }
  __syncthreads();

  // ---- deferred publish of previous phase's h (wave0): drain then relaxed flag store ----
  unsigned* flg = (G == 0) ? (flags + NWG) : flags;
  const unsigned v = (unsigned)(t + 1 + G);
  if (tid == 0) {
    __builtin_amdgcn_sched_barrier(0);
    __builtin_amdgcn_s_waitcnt(0);      // hbuf/out stores of prev phase (and prologue prefill)
    __builtin_amdgcn_sched_barrier(0);
    __hip_atomic_store(&flg[wgid], v, __ATOMIC_RELAXED, SCOPE_AGENT);
  }

  // ---- x-part matvec for this group's 8 batches ----
  float4 xacc[8];
#pragma unroll
  for (int bi = 0; bi < 8; ++bi) {
    const float* xbase = sh_x + (RB + bi) * DD_ + lane * 4;
    float4 a = make_float4(0.f, 0.f, 0.f, 0.f);
#pragma unroll
    for (int q = 0; q < 4; ++q) {
      float4 xv = *(const float4*)(xbase + q * 256);
      fma4(a, xv.x, wi_r[4*q+0]); fma4(a, xv.y, wi_r[4*q+1]);
      fma4(a, xv.z, wi_r[4*q+2]); fma4(a, xv.w, wi_r[4*q+3]);
    }
    xacc[bi] = a;
  }

  // ---- all-wave spin: everyone published v for this flag array ----
  {
    for (;;) {
      unsigned f0 = __hip_atomic_load(&flg[lane],       __ATOMIC_RELAXED, SCOPE_AGENT);
      unsigned f1 = __hip_atomic_load(&flg[lane + 64],  __ATOMIC_RELAXED, SCOPE_AGENT);
      unsigned f2 = __hip_atomic_load(&flg[lane + 128], __ATOMIC_RELAXED, SCOPE_AGENT);
      unsigned f3 = __hip_atomic_load(&flg[lane + 192], __ATOMIC_RELAXED, SCOPE_AGENT);
      int ok = (f0 >= v) && (f1 >= v) && (f2 >= v) && (f3 >= v);
      if (__all(ok)) break;
      __builtin_amdgcn_s_sleep(1);
    }
    __builtin_amdgcn_sched_barrier(0);
  }

  // ---- issue gather of OTHER group's h + its x prefetch (consumed next phase entry);
  //      flight time hides under the h-matvec + reduce below ----
  if (G == 0 || t + 1 < TT_) {
    // G==0: gather h_B(t-1) from B[(t-1)&1]; prefetch x_B(t)
    // G==1: gather h_A(t)   from A[t&1];     prefetch x_A(t+1)
    const int par = (G == 0) ? ((t + 1) & 1) : (t & 1);
    const float* src = hbuf + (G == 0 ? 16384 : 0) + par * 8192;
    const unsigned long long* s8 = (const unsigned long long*)src;
#pragma unroll
    for (int r = 0; r < 16; ++r)
      hreg_out[r] = __hip_atomic_load(&s8[r * NT + tid], __ATOMIC_RELAXED, SCOPE_AGENT);
    const float4* xx = (const float4*)x;
    const int xt  = (G == 0) ? t : (t + 1);
    const int rb2 = (G == 0) ? 8 : 0;
#pragma unroll
    for (int r = 0; r < 8; ++r) {
      int f4 = r * NT + tid;
      int b = rb2 + (f4 >> 8), k4 = f4 & 255;
      xreg_out[r] = xx[(size_t)b * (TT_ * DD_ / 4) + (size_t)xt * (DD_ / 4) + k4];
    }
  }

  // ---- h-part matvec (xacc pre-added) + cross-lane reduce: 2 batch-groups of 4 ----
#pragma unroll 1
  for (int bg = 0; bg < 2; ++bg) {
#pragma unroll
    for (int bb = 0; bb < 4; ++bb) {
      const int bl = bg * 4 + bb;
      const float* hbase = sh_h + (RB + bl) * DD_ + lane * 4;
      float4 acc = xacc[bl];
#pragma unroll
      for (int q = 0; q < 4; ++q) {
        float4 hv = *(const float4*)(hbase + q * 256);
        fma4(acc, hv.x, wh_r[4*q+0]);
        fma4(acc, hv.y, wh_r[4*q+1]);
        fma4(acc, hv.z, wh_r[4*q+2]);
        fma4(acc, hv.w, wh_r[4*q+3]);
      }
      float* pp = sh_part + bb * 1040 + (w * 4) * 65 + lane;
      pp[0]   = acc.x;
      pp[65]  = acc.y;
      pp[130] = acc.z;
      pp[195] = acc.w;
    }
    __syncthreads();
    {
      const int bb2 = tid >> 6, lc = (tid >> 2) & 15, sq = tid & 3;
      const float* pp = sh_part + bb2 * 1040 + lc * 65 + sq * 16;
      float s = 0.f;
#pragma unroll
      for (int i = 0; i < 16; ++i)
        s += pp[i];
      s += __shfl_xor(s, 1);
      s += __shfl_xor(s, 2);
      if (sq == 0)
        sh_yg[RB + bg * 4 + bb2][lc] = s + sh_bias[lc];
    }
    __syncthreads();
  }

  // ---- pointwise for this group (half of wave0): lanes [32G, 32G+32) ----
  if ((tid >> 5) == G) {
    const int cb = tid >> 2, jj = tid & 3;   // cb in [RB, RB+8)
    float gi = sigm_f(sh_yg[cb][jj]);
    float gf = sigm_f(sh_yg[cb][4 + jj]);
    float gg = tanh_f(sh_yg[cb][8 + jj]);
    float go = sigm_f(sh_yg[cb][12 + jj]);
    c_state = gf * c_state + gi * gg;
    float hn = go * tanh_f(c_state);
    float* hb = hbuf + (G ? 16384 : 0) + (t & 1) * 8192;
    __hip_atomic_store(&hb[(cb - RB) * DD_ + wgid * 4 + jj], hn, __ATOMIC_RELAXED, SCOPE_AGENT);
    __builtin_nontemporal_store(hn, &out[(size_t)cb * (TT_ * DD_) + (size_t)t * DD_ + wgid * 4 + jj]);
    if (t == TT_ - 1) {
      carry_out[cb * (DD_ * 2) + (wgid * 4 + jj) * 2 + 0] = hn;
      carry_out[cb * (DD_ * 2) + (wgid * 4 + jj) * 2 + 1] = c_state;
    }
  }
  // no drain here: next phase's entry wait + deferred publish covers it
}

__global__ __launch_bounds__(NT, 1) void lstm_persist(
    const float* __restrict__ x, const float* __restrict__ carry,
    const float* __restrict__ Wi, const float* __restrict__ Wh,
    const float* __restrict__ bias,
    float* __restrict__ out, float* __restrict__ carry_out,
    float* __restrict__ hbuf, unsigned* __restrict__ flags)
{
  __shared__ float sh_h[BB_ * DD_];          // 64 KB   [b][k]
  __shared__ float sh_x[BB_ * DD_];          // 64 KB   [b][k]
  __shared__ float sh_part[4 * 1040];        // [bb][col(16), pitch 65][lane]
  __shared__ float sh_yg[16][16];            // [b][localcol = gate*4+jj]
  __shared__ float sh_bias[16];

  const int tid  = threadIdx.x;
  const int wgid = blockIdx.x;       // owns gate columns wgid*4 + {0..3} per gate
  const int w    = tid >> 6;         // wave index == gate index
  const int lane = tid & 63;

  // ---- weights -> registers. Thread rows: k = q*256 + lane*4 + c (q,c in 0..3).
  float4 wi_r[16], wh_r[16];
  {
    const float4* Wi4 = (const float4*)Wi;
    const float4* Wh4 = (const float4*)Wh;
    const int cbase = w * 256 + wgid;
#pragma unroll
    for (int q = 0; q < 4; ++q)
#pragma unroll
      for (int c = 0; c < 4; ++c) {
        const int row = q * 256 + lane * 4 + c;
        wi_r[q * 4 + c] = Wi4[(size_t)row * (GG_ / 4) + cbase];
        wh_r[q * 4 + c] = Wh4[(size_t)row * (GG_ / 4) + cbase];
      }
  }
  if (tid < 16)
    sh_bias[tid] = bias[(tid >> 2) * DD_ + wgid * 4 + (tid & 3)];

  // ---- preload h0 (all 16 batches) and x_A(0) (batches 0-7) into LDS ----
  for (int f = tid; f < BB_ * DD_; f += NT)
    sh_h[f] = carry[(f >> 10) * (DD_ * 2) + (f & 1023) * 2];
  {
    const float4* xx = (const float4*)x;
#pragma unroll
    for (int r = 0; r < 8; ++r) {
      int f4 = r * NT + tid;
      int b = f4 >> 8, k4 = f4 & 255;
      ((float4*)sh_x)[f4] = xx[(size_t)b * (TT_ * DD_ / 4) + k4];
    }
  }

  // cell state lives in wave0 registers: lane = b*4 + jj
  float c_state = 0.f;
  if (tid < 64)
    c_state = carry[(tid >> 2) * (DD_ * 2) + (wgid * 4 + (tid & 3)) * 2 + 1];

  // prefill hbuf_B[1] with h0 of batches 8-15 (own column slice);
  // drained + published (flags_B = 1) at phase A(0).
  if ((tid >> 5) == 1) {
    const int cb = tid >> 2, jj = tid & 3;   // cb 8..15
    float h0v = carry[cb * (DD_ * 2) + (wgid * 4 + jj) * 2];
    __hip_atomic_store(&hbuf[24576 + (cb - 8) * DD_ + wgid * 4 + jj], h0v,
                       __ATOMIC_RELAXED, SCOPE_AGENT);
  }
  __syncthreads();

  unsigned long long hA[16], hB[16];
  float4 xA[8], xB[8];

  for (int t = 0; t < TT_; ++t) {
    run_phase<0>(t, wgid, tid, w, lane, wi_r, wh_r, sh_h, sh_x, sh_part, sh_yg,
                 sh_bias, x, out, carry_out, hbuf, flags, c_state, hA, xA, hB, xB);
    run_phase<1>(t, wgid, tid, w, lane, wi_r, wh_r, sh_h, sh_x, sh_part, sh_yg,
                 sh_bias, x, out, carry_out, hbuf, flags, c_state, hB, xB, hA, xA);
  }
}

extern "C" void kernel_launch(void* const* d_in, const int* in_sizes, int n_in,
                              void* d_out, int out_size, void* d_ws, size_t ws_size,
                              hipStream_t stream) {
  const float* x     = (const float*)d_in[0];
  const float* carry = (const float*)d_in[1];
  const float* Wi    = (const float*)d_in[2];
  const float* Wh    = (const float*)d_in[3];
  const float* bias  = (const float*)d_in[4];
  float* out       = (float*)d_out;
  float* carry_out = out + (size_t)BB_ * TT_ * DD_;
  float* hbuf      = (float*)d_ws;   // 4 x 8*D floats (A0,A1,B0,B1)
  unsigned* flags  = (unsigned*)((char*)d_ws + (size_t)4 * 8 * DD_ * sizeof(float));

  (void)hipMemsetAsync(flags, 0, 2 * NWG * sizeof(unsigned), stream);

  void* args[] = {(void*)&x, (void*)&carry, (void*)&Wi, (void*)&Wh, (void*)&bias,
                  (void*)&out, (void*)&carry_out, (void*)&hbuf, (void*)&flags};
  (void)hipLaunchCooperativeKernel((void*)lstm_persist, dim3(NWG), dim3(NT),
                                   args, 0, stream);
}

// Round 3
// 33879.251 us; speedup vs baseline: 1.1041x; 1.1041x over previous
//
#include <hip/hip_runtime.h>

// Problem constants (B,T,D fixed by setup_inputs)
#define BB_ 16
#define TT_ 2048
#define DD_ 1024
#define GG_ 4096   // 4*D
#define NWG 256
#define NT  256
#define SCOPE_AGENT __HIP_MEMORY_SCOPE_AGENT

// Persistent-LSTM, round 6: round-3 skeleton + release/acquire cached h-gather.
//  - Round-4 lesson: per-step cost is TRAFFIC-proportional; the agent-scope
//    broadcast all-gather (256 CUs x 64KB from MALL = 16 MB/step) dominates.
//  - Fix: producers release h (agent write-through stores + s_waitcnt(0) before
//    flag store, unchanged). Consumers, after the flag spin, execute an
//    agent-scope ACQUIRE fence (compiler emits buffer_inv: drops stale L1/L2
//    lines) and then gather hbuf with PLAIN CACHED loads. Per XCD, the first
//    requester of each line misses to MALL; the other 31 CUs are served by the
//    local L2 (miss-merge/hits). EA gather traffic: 16 MB/step -> ~0.5 MB/step.
//  - No new protocol: flags/hbuf identical to the passing round-3 kernel;
//    workspace footprint identical (132 KB). buffer_inv preserves dirty lines
//    (the arch's own fence sequences rely on this), so out-stores are safe.
//  - Arithmetic order identical to round 3 -> identical results.

__device__ __forceinline__ void fma4(float4& a, float s, const float4& w) {
  a.x = fmaf(s, w.x, a.x);
  a.y = fmaf(s, w.y, a.y);
  a.z = fmaf(s, w.z, a.z);
  a.w = fmaf(s, w.w, a.w);
}

__device__ __forceinline__ float sigm_f(float v) { return 1.f / (1.f + __expf(-v)); }
__device__ __forceinline__ float tanh_f(float v) { return 1.f - 2.f / (1.f + __expf(2.f * v)); }

__global__ __launch_bounds__(NT, 1) void lstm_persist(
    const float* __restrict__ x, const float* __restrict__ carry,
    const float* __restrict__ Wi, const float* __restrict__ Wh,
    const float* __restrict__ bias,
    float* __restrict__ out, float* __restrict__ carry_out,
    float* __restrict__ hbuf, unsigned* __restrict__ flags)
{
  __shared__ float sh_h[BB_ * DD_];          // 64 KB   [b][k]
  __shared__ float sh_x[BB_ * DD_];          // 64 KB   [b][k]
  __shared__ float sh_part[4 * 1040];        // [bb][col(16), pitch 65][lane]
  __shared__ float sh_yg[16][16];            // [b][localcol = gate*4+jj]
  __shared__ float sh_bias[16];

  const int tid  = threadIdx.x;
  const int wgid = blockIdx.x;       // owns gate columns wgid*4 + {0..3} per gate
  const int w    = tid >> 6;         // wave index == gate index
  const int lane = tid & 63;

  // ---- weights -> registers. Thread rows: k = q*256 + lane*4 + c (q,c in 0..3).
  float4 wi_r[16], wh_r[16];
  {
    const float4* Wi4 = (const float4*)Wi;
    const float4* Wh4 = (const float4*)Wh;
    const int cbase = w * 256 + wgid;
#pragma unroll
    for (int q = 0; q < 4; ++q)
#pragma unroll
      for (int c = 0; c < 4; ++c) {
        const int row = q * 256 + lane * 4 + c;
        wi_r[q * 4 + c] = Wi4[(size_t)row * (GG_ / 4) + cbase];
        wh_r[q * 4 + c] = Wh4[(size_t)row * (GG_ / 4) + cbase];
      }
  }
  if (tid < 16)
    sh_bias[tid] = bias[(tid >> 2) * DD_ + wgid * 4 + (tid & 3)];

  // ---- preload h0 (carry[...,0], stride-2) and x_t=0 into LDS ----
  for (int f = tid; f < BB_ * DD_; f += NT)
    sh_h[f] = carry[(f >> 10) * (DD_ * 2) + (f & 1023) * 2];
  {
    const float4* xx = (const float4*)x;
#pragma unroll
    for (int r = 0; r < 16; ++r) {
      int f4 = r * NT + tid;
      int b = f4 >> 8, k4 = f4 & 255;
      ((float4*)sh_x)[f4] = xx[(size_t)b * (TT_ * DD_ / 4) + k4];
    }
  }

  // cell state lives in wave0 registers: lane = b*4 + jj
  float c_state = 0.f;
  if (tid < 64)
    c_state = carry[(tid >> 2) * (DD_ * 2) + (wgid * 4 + (tid & 3)) * 2 + 1];

  __syncthreads();

  // ---- prologue: xacc for t=0 from sh_x ----
  float4 xacc[16];
#pragma unroll
  for (int bidx = 0; bidx < 16; ++bidx) {
    const float* xbase = sh_x + bidx * DD_ + lane * 4;
    float4 a = make_float4(0.f, 0.f, 0.f, 0.f);
#pragma unroll
    for (int q = 0; q < 4; ++q) {
      float4 xv = *(const float4*)(xbase + q * 256);
      fma4(a, xv.x, wi_r[4*q+0]); fma4(a, xv.y, wi_r[4*q+1]);
      fma4(a, xv.z, wi_r[4*q+2]); fma4(a, xv.w, wi_r[4*q+3]);
    }
    xacc[bidx] = a;
  }

  float* hb0 = hbuf;
  float* hb1 = hbuf + BB_ * DD_;

  for (int t = 0; t < TT_; ++t) {
    // ======== h-part matvec (xacc pre-added): 4 batch-groups of 4 ========
#pragma unroll 1
    for (int bg = 0; bg < 4; ++bg) {
#pragma unroll
      for (int bb = 0; bb < 4; ++bb) {
        const int bidx = bg * 4 + bb;
        const float* hbase = sh_h + bidx * DD_ + lane * 4;
        float4 acc = xacc[bidx];
#pragma unroll
        for (int q = 0; q < 4; ++q) {
          float4 hv = *(const float4*)(hbase + q * 256);
          fma4(acc, hv.x, wh_r[4*q+0]);
          fma4(acc, hv.y, wh_r[4*q+1]);
          fma4(acc, hv.z, wh_r[4*q+2]);
          fma4(acc, hv.w, wh_r[4*q+3]);
        }
        float* pp = sh_part + bb * 1040 + (w * 4) * 65 + lane;
        pp[0]   = acc.x;
        pp[65]  = acc.y;
        pp[130] = acc.z;
        pp[195] = acc.w;
      }
      __syncthreads();
      {
        const int bb2 = tid >> 6, lc = (tid >> 2) & 15, sq = tid & 3;
        const float* pp = sh_part + bb2 * 1040 + lc * 65 + sq * 16;
        float s = 0.f;
#pragma unroll
        for (int i = 0; i < 16; ++i)
          s += pp[i];
        s += __shfl_xor(s, 1);
        s += __shfl_xor(s, 2);
        if (sq == 0)
          sh_yg[bg * 4 + bb2][lc] = s + sh_bias[lc];
      }
      __syncthreads();
    }

    // ======== pointwise: wave0, lane = b*4 + jj ========
    float* hb_nxt = ((t + 1) & 1) ? hb1 : hb0;
    if (tid < 64) {
      const int cb = tid >> 2, jj = tid & 3;
      float gi = sigm_f(sh_yg[cb][jj]);
      float gf = sigm_f(sh_yg[cb][4 + jj]);
      float gg = tanh_f(sh_yg[cb][8 + jj]);
      float go = sigm_f(sh_yg[cb][12 + jj]);
      c_state = gf * c_state + gi * gg;
      float hn = go * tanh_f(c_state);
      __builtin_nontemporal_store(hn, &out[(size_t)cb * (TT_ * DD_) + (size_t)t * DD_ + wgid * 4 + jj]);
      __hip_atomic_store(&hb_nxt[cb * DD_ + wgid * 4 + jj], hn, __ATOMIC_RELAXED, SCOPE_AGENT);
      if (t == TT_ - 1) {
        carry_out[cb * (DD_ * 2) + (wgid * 4 + jj) * 2 + 0] = hn;
        carry_out[cb * (DD_ * 2) + (wgid * 4 + jj) * 2 + 1] = c_state;
      }
    }

    if (t + 1 < TT_) {
      // publish: wave0's h stores are agent write-through; drain, then flag store.
      if (tid == 0) {
        __builtin_amdgcn_sched_barrier(0);
        __builtin_amdgcn_s_waitcnt(0);
        __builtin_amdgcn_sched_barrier(0);
        __hip_atomic_store(&flags[wgid], (unsigned)(t + 1), __ATOMIC_RELAXED, SCOPE_AGENT);
      }

      // ======== prefetch x[t+1] into LDS (barrier shadow) ========
      {
        const float4* xx = (const float4*)x;
#pragma unroll
        for (int r = 0; r < 16; ++r) {
          int f4 = r * NT + tid;
          int b = f4 >> 8, k4 = f4 & 255;
          ((float4*)sh_x)[f4] = xx[(size_t)b * (TT_ * DD_ / 4) + (size_t)(t + 1) * (DD_ / 4) + k4];
        }
      }
      __syncthreads();

      // ======== x-part matvec for t+1 (barrier shadow) ========
#pragma unroll
      for (int bidx = 0; bidx < 16; ++bidx) {
        const float* xbase = sh_x + bidx * DD_ + lane * 4;
        float4 a = make_float4(0.f, 0.f, 0.f, 0.f);
#pragma unroll
        for (int q = 0; q < 4; ++q) {
          float4 xv = *(const float4*)(xbase + q * 256);
          fma4(a, xv.x, wi_r[4*q+0]); fma4(a, xv.y, wi_r[4*q+1]);
          fma4(a, xv.z, wi_r[4*q+2]); fma4(a, xv.w, wi_r[4*q+3]);
        }
        xacc[bidx] = a;
      }

      // ======== spin: wave0 polls all 256 flags (u64 pairs, 2 loads/lane) ========
      if (tid < 64) {
        const unsigned tv = (unsigned)(t + 1);
        const unsigned long long* f8 = (const unsigned long long*)flags;
        for (;;) {
          unsigned long long a = __hip_atomic_load(&f8[lane],      __ATOMIC_RELAXED, SCOPE_AGENT);
          unsigned long long b = __hip_atomic_load(&f8[lane + 64], __ATOMIC_RELAXED, SCOPE_AGENT);
          int ok = ((unsigned)a >= tv) && ((unsigned)(a >> 32) >= tv) &&
                   ((unsigned)b >= tv) && ((unsigned)(b >> 32) >= tv);
          if (__all(ok)) break;
          __builtin_amdgcn_s_sleep(1);
        }
      }
      __syncthreads();

      // ======== all-gather new h: ACQUIRE fence, then CACHED reads ========
      // Fence (buffer_inv) drops stale L1/L2 lines; plain loads then miss to
      // MALL once per line per XCD and the other 31 CUs are served by the
      // local L2 -> EA gather traffic ~32x lower than agent-scope loads.
      __builtin_amdgcn_fence(__ATOMIC_ACQUIRE, "agent");
      {
        const float4* hb4 = (const float4*)hb_nxt;
#pragma unroll
        for (int r = 0; r < 16; ++r) {
          int idx = r * NT + tid;
          ((float4*)sh_h)[idx] = hb4[idx];
        }
      }
      __syncthreads();
    }
  }
}

extern "C" void kernel_launch(void* const* d_in, const int* in_sizes, int n_in,
                              void* d_out, int out_size, void* d_ws, size_t ws_size,
                              hipStream_t stream) {
  const float* x     = (const float*)d_in[0];
  const float* carry = (const float*)d_in[1];
  const float* Wi    = (const float*)d_in[2];
  const float* Wh    = (const float*)d_in[3];
  const float* bias  = (const float*)d_in[4];
  float* out       = (float*)d_out;
  float* carry_out = out + (size_t)BB_ * TT_ * DD_;
  float* hbuf      = (float*)d_ws;   // 2 * B*D floats, written before read each step
  unsigned* flags  = (unsigned*)((char*)d_ws + (size_t)2 * BB_ * DD_ * sizeof(float));

  (void)hipMemsetAsync(flags, 0, NWG * sizeof(unsigned), stream);

  void* args[] = {(void*)&x, (void*)&carry, (void*)&Wi, (void*)&Wh, (void*)&bias,
                  (void*)&out, (void*)&carry_out, (void*)&hbuf, (void*)&flags};
  (void)hipLaunchCooperativeKernel((void*)lstm_persist, dim3(NWG), dim3(NT),
                                   args, 0, stream);
}

// Round 5
// 20205.937 us; speedup vs baseline: 1.8513x; 1.6767x over previous
//
#include <hip/hip_runtime.h>

// Problem constants (B,T,D fixed by setup_inputs)
#define BB_ 16
#define TT_ 2048
#define DD_ 1024
#define GG_ 4096   // 4*D
#define NWG 256
#define NT  256
#define SCOPE_AGENT __HIP_MEMORY_SCOPE_AGENT

// Persistent-LSTM, round 8: round-3 protocol + latency-overlap rescheduling,
// WITHOUT global_load_lds (de-risked resubmission of round 7 after container
// failure gave no data; x-prefetch restored to the proven round-3 form).
//  - (a) Pointwise store order: h-store -> s_waitcnt(0) -> flag -> NT out-store.
//        The drain no longer waits for the non-temporal HBM out-store.
//  - (b) Spin owned by WAVE1, placed after x-matvec(batches 0-7): flag
//        propagation hides under prefetch+a1; wave0's drain overlaps them.
//  - (c) Gather of h(t+1) issued into registers right after the spin barrier;
//        x-matvec(batches 8-15) runs in its shadow; one vmcnt(0), LDS commit.
//  - Flag protocol, hbuf layout, workspace, arithmetic order: identical to the
//    round-3 kernel that passed (absmax 0.00390625).
//  - Race audit: prefetch writes sh_x after commit-sync of prev step (last
//    readers: prev a2); a1 reads rows 0-7 after prefetch sync; gather loads
//    drained by commit vmcnt(0) before sh_h writes; sh_h written after spin
//    barrier (last readers: this step's h-matvec). Buffer reuse: gather of
//    hbuf[p] completes (commit vmcnt(0)) before this WG publishes t+2, which
//    gates any WG overwriting hbuf[p] at step t+2 -> >1-step margin.

__device__ __forceinline__ void fma4(float4& a, float s, const float4& w) {
  a.x = fmaf(s, w.x, a.x);
  a.y = fmaf(s, w.y, a.y);
  a.z = fmaf(s, w.z, a.z);
  a.w = fmaf(s, w.w, a.w);
}

__device__ __forceinline__ float sigm_f(float v) { return 1.f / (1.f + __expf(-v)); }
__device__ __forceinline__ float tanh_f(float v) { return 1.f - 2.f / (1.f + __expf(2.f * v)); }

__global__ __launch_bounds__(NT, 1) void lstm_persist(
    const float* __restrict__ x, const float* __restrict__ carry,
    const float* __restrict__ Wi, const float* __restrict__ Wh,
    const float* __restrict__ bias,
    float* __restrict__ out, float* __restrict__ carry_out,
    float* __restrict__ hbuf, unsigned* __restrict__ flags)
{
  __shared__ float sh_h[BB_ * DD_];          // 64 KB   [b][k]
  __shared__ float sh_x[BB_ * DD_];          // 64 KB   [b][k]
  __shared__ float sh_part[4 * 1040];        // [bb][col(16), pitch 65][lane]
  __shared__ float sh_yg[16][16];            // [b][localcol = gate*4+jj]
  __shared__ float sh_bias[16];

  const int tid  = threadIdx.x;
  const int wgid = blockIdx.x;       // owns gate columns wgid*4 + {0..3} per gate
  const int w    = tid >> 6;         // wave index == gate index
  const int lane = tid & 63;

  // ---- weights -> registers. Thread rows: k = q*256 + lane*4 + c (q,c in 0..3).
  float4 wi_r[16], wh_r[16];
  {
    const float4* Wi4 = (const float4*)Wi;
    const float4* Wh4 = (const float4*)Wh;
    const int cbase = w * 256 + wgid;
#pragma unroll
    for (int q = 0; q < 4; ++q)
#pragma unroll
      for (int c = 0; c < 4; ++c) {
        const int row = q * 256 + lane * 4 + c;
        wi_r[q * 4 + c] = Wi4[(size_t)row * (GG_ / 4) + cbase];
        wh_r[q * 4 + c] = Wh4[(size_t)row * (GG_ / 4) + cbase];
      }
  }
  if (tid < 16)
    sh_bias[tid] = bias[(tid >> 2) * DD_ + wgid * 4 + (tid & 3)];

  // ---- preload h0 (carry[...,0], stride-2) and x_t=0 into LDS ----
  for (int f = tid; f < BB_ * DD_; f += NT)
    sh_h[f] = carry[(f >> 10) * (DD_ * 2) + (f & 1023) * 2];
  {
    const float4* xx = (const float4*)x;
#pragma unroll
    for (int r = 0; r < 16; ++r) {
      int f4 = r * NT + tid;
      int b = f4 >> 8, k4 = f4 & 255;
      ((float4*)sh_x)[f4] = xx[(size_t)b * (TT_ * DD_ / 4) + k4];
    }
  }

  // cell state lives in wave0 registers: lane = b*4 + jj
  float c_state = 0.f;
  if (tid < 64)
    c_state = carry[(tid >> 2) * (DD_ * 2) + (wgid * 4 + (tid & 3)) * 2 + 1];

  __syncthreads();

  // ---- prologue: xacc for t=0 from sh_x = x[0] ----
  float4 xacc[16];
#pragma unroll
  for (int bidx = 0; bidx < 16; ++bidx) {
    const float* xbase = sh_x + bidx * DD_ + lane * 4;
    float4 a = make_float4(0.f, 0.f, 0.f, 0.f);
#pragma unroll
    for (int q = 0; q < 4; ++q) {
      float4 xv = *(const float4*)(xbase + q * 256);
      fma4(a, xv.x, wi_r[4*q+0]); fma4(a, xv.y, wi_r[4*q+1]);
      fma4(a, xv.z, wi_r[4*q+2]); fma4(a, xv.w, wi_r[4*q+3]);
    }
    xacc[bidx] = a;
  }

  float* hb0 = hbuf;
  float* hb1 = hbuf + BB_ * DD_;

  for (int t = 0; t < TT_; ++t) {
    // ======== h-part matvec (xacc pre-added): 4 batch-groups of 4 ========
#pragma unroll 1
    for (int bg = 0; bg < 4; ++bg) {
#pragma unroll
      for (int bb = 0; bb < 4; ++bb) {
        const int bidx = bg * 4 + bb;
        const float* hbase = sh_h + bidx * DD_ + lane * 4;
        float4 acc = xacc[bidx];
#pragma unroll
        for (int q = 0; q < 4; ++q) {
          float4 hv = *(const float4*)(hbase + q * 256);
          fma4(acc, hv.x, wh_r[4*q+0]);
          fma4(acc, hv.y, wh_r[4*q+1]);
          fma4(acc, hv.z, wh_r[4*q+2]);
          fma4(acc, hv.w, wh_r[4*q+3]);
        }
        float* pp = sh_part + bb * 1040 + (w * 4) * 65 + lane;
        pp[0]   = acc.x;
        pp[65]  = acc.y;
        pp[130] = acc.z;
        pp[195] = acc.w;
      }
      __syncthreads();
      {
        const int bb2 = tid >> 6, lc = (tid >> 2) & 15, sq = tid & 3;
        const float* pp = sh_part + bb2 * 1040 + lc * 65 + sq * 16;
        float s = 0.f;
#pragma unroll
        for (int i = 0; i < 16; ++i)
          s += pp[i];
        s += __shfl_xor(s, 1);
        s += __shfl_xor(s, 2);
        if (sq == 0)
          sh_yg[bg * 4 + bb2][lc] = s + sh_bias[lc];
      }
      __syncthreads();
    }

    // ======== pointwise: wave0, lane = b*4 + jj ========
    // Order: h-store -> drain -> flag -> NT out-store. The drain waits only on
    // the 16B/lane h-stores to MALL, not the HBM out-store.
    float* hb_nxt = ((t + 1) & 1) ? hb1 : hb0;
    if (tid < 64) {
      const int cb = tid >> 2, jj = tid & 3;
      float gi = sigm_f(sh_yg[cb][jj]);
      float gf = sigm_f(sh_yg[cb][4 + jj]);
      float gg = tanh_f(sh_yg[cb][8 + jj]);
      float go = sigm_f(sh_yg[cb][12 + jj]);
      c_state = gf * c_state + gi * gg;
      float hn = go * tanh_f(c_state);
      __hip_atomic_store(&hb_nxt[cb * DD_ + wgid * 4 + jj], hn, __ATOMIC_RELAXED, SCOPE_AGENT);
      __builtin_amdgcn_sched_barrier(0);
      __builtin_amdgcn_s_waitcnt(0);          // wave-wide: drains all 64 lanes' h-stores
      __builtin_amdgcn_sched_barrier(0);
      if (tid == 0)
        __hip_atomic_store(&flags[wgid], (unsigned)(t + 1), __ATOMIC_RELAXED, SCOPE_AGENT);
      __builtin_amdgcn_sched_barrier(0);
      __builtin_nontemporal_store(hn, &out[(size_t)cb * (TT_ * DD_) + (size_t)t * DD_ + wgid * 4 + jj]);
      if (t == TT_ - 1) {
        carry_out[cb * (DD_ * 2) + (wgid * 4 + jj) * 2 + 0] = hn;
        carry_out[cb * (DD_ * 2) + (wgid * 4 + jj) * 2 + 1] = c_state;
      }
    }

    if (t + 1 < TT_) {
      // ======== prefetch x[t+1] into LDS (flag-propagation shadow) ========
      {
        const float4* xx = (const float4*)x;
#pragma unroll
        for (int r = 0; r < 16; ++r) {
          int f4 = r * NT + tid;
          int b = f4 >> 8, k4 = f4 & 255;
          ((float4*)sh_x)[f4] = xx[(size_t)b * (TT_ * DD_ / 4) + (size_t)(t + 1) * (DD_ / 4) + k4];
        }
      }
      __syncthreads();

      // ---- a1: x-part matvec for t+1, batches 0..7 (still in the shadow;
      //          wave0 joins late after its drain, overlapped) ----
#pragma unroll
      for (int bidx = 0; bidx < 8; ++bidx) {
        const float* xbase = sh_x + bidx * DD_ + lane * 4;
        float4 a = make_float4(0.f, 0.f, 0.f, 0.f);
#pragma unroll
        for (int q = 0; q < 4; ++q) {
          float4 xv = *(const float4*)(xbase + q * 256);
          fma4(a, xv.x, wi_r[4*q+0]); fma4(a, xv.y, wi_r[4*q+1]);
          fma4(a, xv.z, wi_r[4*q+2]); fma4(a, xv.w, wi_r[4*q+3]);
        }
        xacc[bidx] = a;
      }

      // ---- spin: WAVE1 polls all 256 flags (u64 pairs); waves 0,2,3 park ----
      if (tid >= 64 && tid < 128) {
        const unsigned tv = (unsigned)(t + 1);
        const unsigned long long* f8 = (const unsigned long long*)flags;
        for (;;) {
          unsigned long long a = __hip_atomic_load(&f8[lane],      __ATOMIC_RELAXED, SCOPE_AGENT);
          unsigned long long b = __hip_atomic_load(&f8[lane + 64], __ATOMIC_RELAXED, SCOPE_AGENT);
          int ok = ((unsigned)a >= tv) && ((unsigned)(a >> 32) >= tv) &&
                   ((unsigned)b >= tv) && ((unsigned)(b >> 32) >= tv);
          if (__all(ok)) break;
          __builtin_amdgcn_s_sleep(1);
        }
      }
      __syncthreads();

      // ---- gather h(t+1) into registers (latency hidden by a2 below) ----
      unsigned long long hreg[32];
      {
        const unsigned long long* hb8 = (const unsigned long long*)hb_nxt;
#pragma unroll
        for (int r = 0; r < 32; ++r)
          hreg[r] = __hip_atomic_load(hb8 + r * NT + tid, __ATOMIC_RELAXED, SCOPE_AGENT);
      }
      __builtin_amdgcn_sched_barrier(0);   // pin gather issue above a2

      // ---- a2: x-part matvec for t+1, batches 8..15 (gather shadow) ----
#pragma unroll
      for (int bidx = 8; bidx < 16; ++bidx) {
        const float* xbase = sh_x + bidx * DD_ + lane * 4;
        float4 a = make_float4(0.f, 0.f, 0.f, 0.f);
#pragma unroll
        for (int q = 0; q < 4; ++q) {
          float4 xv = *(const float4*)(xbase + q * 256);
          fma4(a, xv.x, wi_r[4*q+0]); fma4(a, xv.y, wi_r[4*q+1]);
          fma4(a, xv.z, wi_r[4*q+2]); fma4(a, xv.w, wi_r[4*q+3]);
        }
        xacc[bidx] = a;
      }

      // ---- commit: drain gather, write h(t+1) to LDS ----
      asm volatile("s_waitcnt vmcnt(0)" ::: "memory");
      __builtin_amdgcn_sched_barrier(0);
      {
        unsigned long long* sh8 = (unsigned long long*)sh_h;
#pragma unroll
        for (int r = 0; r < 32; ++r)
          sh8[r * NT + tid] = hreg[r];
      }
      __syncthreads();
    }
  }
}

extern "C" void kernel_launch(void* const* d_in, const int* in_sizes, int n_in,
                              void* d_out, int out_size, void* d_ws, size_t ws_size,
                              hipStream_t stream) {
  const float* x     = (const float*)d_in[0];
  const float* carry = (const float*)d_in[1];
  const float* Wi    = (const float*)d_in[2];
  const float* Wh    = (const float*)d_in[3];
  const float* bias  = (const float*)d_in[4];
  float* out       = (float*)d_out;
  float* carry_out = out + (size_t)BB_ * TT_ * DD_;
  float* hbuf      = (float*)d_ws;   // 2 * B*D floats, written before read each step
  unsigned* flags  = (unsigned*)((char*)d_ws + (size_t)2 * BB_ * DD_ * sizeof(float));

  (void)hipMemsetAsync(flags, 0, NWG * sizeof(unsigned), stream);

  void* args[] = {(void*)&x, (void*)&carry, (void*)&Wi, (void*)&Wh, (void*)&bias,
                  (void*)&out, (void*)&carry_out, (void*)&hbuf, (void*)&flags};
  (void)hipLaunchCooperativeKernel((void*)lstm_persist, dim3(NWG), dim3(NT),
                                   args, 0, stream);
}

// Round 6
// 20125.136 us; speedup vs baseline: 1.8587x; 1.0040x over previous
//
#include <hip/hip_runtime.h>

// Problem constants (B,T,D fixed by setup_inputs)
#define BB_ 16
#define TT_ 2048
#define DD_ 1024
#define GG_ 4096   // 4*D
#define NWG 256
#define NT  256
#define SCOPE_AGENT __HIP_MEMORY_SCOPE_AGENT

// Persistent-LSTM, round 9: per-thread producer-pair polling.
//  - Round-8 lesson (confirmed theory): cost = exposed serialized latencies.
//    Remaining chain: publish drain -> flag propagate -> GLOBAL spin consensus
//    -> gather issue -> gather return -> commit.
//  - Key dependence audit: thread tid's gather (u64 slots r*256+tid) reads float
//    cols {2tid,2tid+1, 512+2tid,512+2tid+1} -> produced by exactly TWO WGs:
//    tid>>1 and (tid>>1)+128. So each thread polls only ITS 2 producer flags and
//    issues its gather immediately. The straggler wait now overlaps gather
//    flight + a2 instead of preceding them. No wave1 spin, no spin barrier.
//  - Consensus is re-established at the commit __syncthreads: the 256 threads
//    collectively poll all 256 flags, so past-commit => all flags >= t+1.
//    Buffer-reuse safety (hbuf[p] overwritten at t+2 only after all WGs' t-gathers
//    drained) holds by the same transitivity as round 3/8: Y's vmcnt(0) drains its
//    gather BEFORE Y publishes t+2; X overwrites only after observing >= t+2.
//  - Ordering soundness of relaxed poll->gather (same as round-3/8 spin->gather):
//    gather loads are issued only after the dependent flag-check branch; producer
//    drained h-stores to MALL before its flag store; agent-scope relaxed loads are
//    served at the MALL coherence point -> data is there when the load arrives.
//  - Everything else (arithmetic order, publish order, prefetch, a1/a2 split,
//    commit) identical to round 8 -> absmax must stay exactly 0.00390625.

__device__ __forceinline__ void fma4(float4& a, float s, const float4& w) {
  a.x = fmaf(s, w.x, a.x);
  a.y = fmaf(s, w.y, a.y);
  a.z = fmaf(s, w.z, a.z);
  a.w = fmaf(s, w.w, a.w);
}

__device__ __forceinline__ float sigm_f(float v) { return 1.f / (1.f + __expf(-v)); }
__device__ __forceinline__ float tanh_f(float v) { return 1.f - 2.f / (1.f + __expf(2.f * v)); }

__global__ __launch_bounds__(NT, 1) void lstm_persist(
    const float* __restrict__ x, const float* __restrict__ carry,
    const float* __restrict__ Wi, const float* __restrict__ Wh,
    const float* __restrict__ bias,
    float* __restrict__ out, float* __restrict__ carry_out,
    float* __restrict__ hbuf, unsigned* __restrict__ flags)
{
  __shared__ float sh_h[BB_ * DD_];          // 64 KB   [b][k]
  __shared__ float sh_x[BB_ * DD_];          // 64 KB   [b][k]
  __shared__ float sh_part[4 * 1040];        // [bb][col(16), pitch 65][lane]
  __shared__ float sh_yg[16][16];            // [b][localcol = gate*4+jj]
  __shared__ float sh_bias[16];

  const int tid  = threadIdx.x;
  const int wgid = blockIdx.x;       // owns gate columns wgid*4 + {0..3} per gate
  const int w    = tid >> 6;         // wave index == gate index
  const int lane = tid & 63;

  // ---- weights -> registers. Thread rows: k = q*256 + lane*4 + c (q,c in 0..3).
  float4 wi_r[16], wh_r[16];
  {
    const float4* Wi4 = (const float4*)Wi;
    const float4* Wh4 = (const float4*)Wh;
    const int cbase = w * 256 + wgid;
#pragma unroll
    for (int q = 0; q < 4; ++q)
#pragma unroll
      for (int c = 0; c < 4; ++c) {
        const int row = q * 256 + lane * 4 + c;
        wi_r[q * 4 + c] = Wi4[(size_t)row * (GG_ / 4) + cbase];
        wh_r[q * 4 + c] = Wh4[(size_t)row * (GG_ / 4) + cbase];
      }
  }
  if (tid < 16)
    sh_bias[tid] = bias[(tid >> 2) * DD_ + wgid * 4 + (tid & 3)];

  // ---- preload h0 (carry[...,0], stride-2) and x_t=0 into LDS ----
  for (int f = tid; f < BB_ * DD_; f += NT)
    sh_h[f] = carry[(f >> 10) * (DD_ * 2) + (f & 1023) * 2];
  {
    const float4* xx = (const float4*)x;
#pragma unroll
    for (int r = 0; r < 16; ++r) {
      int f4 = r * NT + tid;
      int b = f4 >> 8, k4 = f4 & 255;
      ((float4*)sh_x)[f4] = xx[(size_t)b * (TT_ * DD_ / 4) + k4];
    }
  }

  // cell state lives in wave0 registers: lane = b*4 + jj
  float c_state = 0.f;
  if (tid < 64)
    c_state = carry[(tid >> 2) * (DD_ * 2) + (wgid * 4 + (tid & 3)) * 2 + 1];

  __syncthreads();

  // ---- prologue: xacc for t=0 from sh_x = x[0] ----
  float4 xacc[16];
#pragma unroll
  for (int bidx = 0; bidx < 16; ++bidx) {
    const float* xbase = sh_x + bidx * DD_ + lane * 4;
    float4 a = make_float4(0.f, 0.f, 0.f, 0.f);
#pragma unroll
    for (int q = 0; q < 4; ++q) {
      float4 xv = *(const float4*)(xbase + q * 256);
      fma4(a, xv.x, wi_r[4*q+0]); fma4(a, xv.y, wi_r[4*q+1]);
      fma4(a, xv.z, wi_r[4*q+2]); fma4(a, xv.w, wi_r[4*q+3]);
    }
    xacc[bidx] = a;
  }

  float* hb0 = hbuf;
  float* hb1 = hbuf + BB_ * DD_;

  // per-thread producer flags for the gather (see header comment)
  const unsigned* const fp0 = &flags[tid >> 1];
  const unsigned* const fp1 = &flags[(tid >> 1) + 128];

  for (int t = 0; t < TT_; ++t) {
    // ======== h-part matvec (xacc pre-added): 4 batch-groups of 4 ========
#pragma unroll 1
    for (int bg = 0; bg < 4; ++bg) {
#pragma unroll
      for (int bb = 0; bb < 4; ++bb) {
        const int bidx = bg * 4 + bb;
        const float* hbase = sh_h + bidx * DD_ + lane * 4;
        float4 acc = xacc[bidx];
#pragma unroll
        for (int q = 0; q < 4; ++q) {
          float4 hv = *(const float4*)(hbase + q * 256);
          fma4(acc, hv.x, wh_r[4*q+0]);
          fma4(acc, hv.y, wh_r[4*q+1]);
          fma4(acc, hv.z, wh_r[4*q+2]);
          fma4(acc, hv.w, wh_r[4*q+3]);
        }
        float* pp = sh_part + bb * 1040 + (w * 4) * 65 + lane;
        pp[0]   = acc.x;
        pp[65]  = acc.y;
        pp[130] = acc.z;
        pp[195] = acc.w;
      }
      __syncthreads();
      {
        const int bb2 = tid >> 6, lc = (tid >> 2) & 15, sq = tid & 3;
        const float* pp = sh_part + bb2 * 1040 + lc * 65 + sq * 16;
        float s = 0.f;
#pragma unroll
        for (int i = 0; i < 16; ++i)
          s += pp[i];
        s += __shfl_xor(s, 1);
        s += __shfl_xor(s, 2);
        if (sq == 0)
          sh_yg[bg * 4 + bb2][lc] = s + sh_bias[lc];
      }
      __syncthreads();
    }

    // ======== pointwise: wave0, lane = b*4 + jj ========
    // Order: h-store -> drain -> flag -> NT out-store.
    float* hb_nxt = ((t + 1) & 1) ? hb1 : hb0;
    if (tid < 64) {
      const int cb = tid >> 2, jj = tid & 3;
      float gi = sigm_f(sh_yg[cb][jj]);
      float gf = sigm_f(sh_yg[cb][4 + jj]);
      float gg = tanh_f(sh_yg[cb][8 + jj]);
      float go = sigm_f(sh_yg[cb][12 + jj]);
      c_state = gf * c_state + gi * gg;
      float hn = go * tanh_f(c_state);
      __hip_atomic_store(&hb_nxt[cb * DD_ + wgid * 4 + jj], hn, __ATOMIC_RELAXED, SCOPE_AGENT);
      __builtin_amdgcn_sched_barrier(0);
      __builtin_amdgcn_s_waitcnt(0);          // wave-wide: drains all 64 lanes' h-stores
      __builtin_amdgcn_sched_barrier(0);
      if (tid == 0)
        __hip_atomic_store(&flags[wgid], (unsigned)(t + 1), __ATOMIC_RELAXED, SCOPE_AGENT);
      __builtin_amdgcn_sched_barrier(0);
      __builtin_nontemporal_store(hn, &out[(size_t)cb * (TT_ * DD_) + (size_t)t * DD_ + wgid * 4 + jj]);
      if (t == TT_ - 1) {
        carry_out[cb * (DD_ * 2) + (wgid * 4 + jj) * 2 + 0] = hn;
        carry_out[cb * (DD_ * 2) + (wgid * 4 + jj) * 2 + 1] = c_state;
      }
    }

    if (t + 1 < TT_) {
      // ======== prefetch x[t+1] into LDS (flag-propagation shadow) ========
      {
        const float4* xx = (const float4*)x;
#pragma unroll
        for (int r = 0; r < 16; ++r) {
          int f4 = r * NT + tid;
          int b = f4 >> 8, k4 = f4 & 255;
          ((float4*)sh_x)[f4] = xx[(size_t)b * (TT_ * DD_ / 4) + (size_t)(t + 1) * (DD_ / 4) + k4];
        }
      }
      __syncthreads();

      // ---- a1: x-part matvec for t+1, batches 0..7 (flag-propagation shadow;
      //          wave0 joins late after its drain, overlapped) ----
#pragma unroll
      for (int bidx = 0; bidx < 8; ++bidx) {
        const float* xbase = sh_x + bidx * DD_ + lane * 4;
        float4 a = make_float4(0.f, 0.f, 0.f, 0.f);
#pragma unroll
        for (int q = 0; q < 4; ++q) {
          float4 xv = *(const float4*)(xbase + q * 256);
          fma4(a, xv.x, wi_r[4*q+0]); fma4(a, xv.y, wi_r[4*q+1]);
          fma4(a, xv.z, wi_r[4*q+2]); fma4(a, xv.w, wi_r[4*q+3]);
        }
        xacc[bidx] = a;
      }

      // ---- per-thread poll of the 2 producer flags (no barrier, no spin wave) ----
      {
        const unsigned tv = (unsigned)(t + 1);
        for (;;) {
          unsigned f0 = __hip_atomic_load(fp0, __ATOMIC_RELAXED, SCOPE_AGENT);
          unsigned f1 = __hip_atomic_load(fp1, __ATOMIC_RELAXED, SCOPE_AGENT);
          if (f0 >= tv && f1 >= tv) break;
          __builtin_amdgcn_s_sleep(1);
        }
        __builtin_amdgcn_sched_barrier(0);
      }

      // ---- gather h(t+1) into registers (issued the moment producers are ready;
      //      latency hidden by a2 below and by other threads' straggler waits) ----
      unsigned long long hreg[32];
      {
        const unsigned long long* hb8 = (const unsigned long long*)hb_nxt;
#pragma unroll
        for (int r = 0; r < 32; ++r)
          hreg[r] = __hip_atomic_load(hb8 + r * NT + tid, __ATOMIC_RELAXED, SCOPE_AGENT);
      }
      __builtin_amdgcn_sched_barrier(0);   // pin gather issue above a2

      // ---- a2: x-part matvec for t+1, batches 8..15 (gather shadow) ----
#pragma unroll
      for (int bidx = 8; bidx < 16; ++bidx) {
        const float* xbase = sh_x + bidx * DD_ + lane * 4;
        float4 a = make_float4(0.f, 0.f, 0.f, 0.f);
#pragma unroll
        for (int q = 0; q < 4; ++q) {
          float4 xv = *(const float4*)(xbase + q * 256);
          fma4(a, xv.x, wi_r[4*q+0]); fma4(a, xv.y, wi_r[4*q+1]);
          fma4(a, xv.z, wi_r[4*q+2]); fma4(a, xv.w, wi_r[4*q+3]);
        }
        xacc[bidx] = a;
      }

      // ---- commit: drain gather, write h(t+1) to LDS ----
      // (this barrier also re-establishes global consensus: collectively the
      //  256 threads' polls cover all 256 flags)
      asm volatile("s_waitcnt vmcnt(0)" ::: "memory");
      __builtin_amdgcn_sched_barrier(0);
      {
        unsigned long long* sh8 = (unsigned long long*)sh_h;
#pragma unroll
        for (int r = 0; r < 32; ++r)
          sh8[r * NT + tid] = hreg[r];
      }
      __syncthreads();
    }
  }
}

extern "C" void kernel_launch(void* const* d_in, const int* in_sizes, int n_in,
                              void* d_out, int out_size, void* d_ws, size_t ws_size,
                              hipStream_t stream) {
  const float* x     = (const float*)d_in[0];
  const float* carry = (const float*)d_in[1];
  const float* Wi    = (const float*)d_in[2];
  const float* Wh    = (const float*)d_in[3];
  const float* bias  = (const float*)d_in[4];
  float* out       = (float*)d_out;
  float* carry_out = out + (size_t)BB_ * TT_ * DD_;
  float* hbuf      = (float*)d_ws;   // 2 * B*D floats, written before read each step
  unsigned* flags  = (unsigned*)((char*)d_ws + (size_t)2 * BB_ * DD_ * sizeof(float));

  (void)hipMemsetAsync(flags, 0, NWG * sizeof(unsigned), stream);

  void* args[] = {(void*)&x, (void*)&carry, (void*)&Wi, (void*)&Wh, (void*)&bias,
                  (void*)&out, (void*)&carry_out, (void*)&hbuf, (void*)&flags};
  (void)hipLaunchCooperativeKernel((void*)lstm_persist, dim3(NWG), dim3(NT),
                                   args, 0, stream);
}

// Round 8
// 19201.241 us; speedup vs baseline: 1.9481x; 1.0481x over previous
//
#include <hip/hip_runtime.h>

// Problem constants (B,T,D fixed by setup_inputs)
#define BB_ 16
#define TT_ 2048
#define DD_ 1024
#define GG_ 4096   // 4*D
#define NWG 256
#define NT  512
#define SCOPE_AGENT __HIP_MEMORY_SCOPE_AGENT

// Persistent-LSTM, round 11: round-9 protocol + 8-wave workgroups (2 waves/SIMD).
//  - Round-10 lesson: tag-in-data corrupted (suspect: u64 store not single-copy
//    atomic across the XCD fabric). Exchange reverted to round-9's PROVEN flag
//    protocol (passed at 20.1 ms).
//  - Round-11 theory: at 256 thr / 1 WG/CU we ran 1 wave/SIMD -> every LDS/VALU
//    latency and barrier skew fully exposed (VALUBusy 30.8%, ~6.8us/step non-VALU).
//    LDS (148KB) forbids 2 WG/CU, but 512 threads gives 8 waves = 2 waves/SIMD:
//    per-wave serial VALU halves, latency hiding doubles. LDS layout unchanged.
//  - Wave mapping: w=tid>>6 (0..7), gate g=w&3, batch-half hf=w>>2.
//    h-matvec bg in 0..3: wave w computes partials for bidx = bg*4 + hf*2 + {0,1}
//    (each (bb,gate) sh_part slot written by exactly one wave, same layout).
//    xacc[8] per thread: local m=bg*2+p -> bidx=bg*4+hf*2+p.
//  - Exchange (round-9 protocol, NT=512 indexing): gather/commit 16 u64/thread
//    (slot r*512+tid, r=0..15 -> row r, float cols 2tid,2tid+1), poll 1 producer
//    flag (wgid = tid>>1). Publish order: h-store -> s_waitcnt(0) -> flag -> NT out.
//    Buffer-reuse transitivity identical to round 9.
//  - Arithmetic order per output element identical to rounds 3-9 -> absmax must
//    stay exactly 0.00390625.

__device__ __forceinline__ void fma4(float4& a, float s, const float4& w) {
  a.x = fmaf(s, w.x, a.x);
  a.y = fmaf(s, w.y, a.y);
  a.z = fmaf(s, w.z, a.z);
  a.w = fmaf(s, w.w, a.w);
}

__device__ __forceinline__ float sigm_f(float v) { return 1.f / (1.f + __expf(-v)); }
__device__ __forceinline__ float tanh_f(float v) { return 1.f - 2.f / (1.f + __expf(2.f * v)); }

__global__ __launch_bounds__(NT, 2) void lstm_persist(
    const float* __restrict__ x, const float* __restrict__ carry,
    const float* __restrict__ Wi, const float* __restrict__ Wh,
    const float* __restrict__ bias,
    float* __restrict__ out, float* __restrict__ carry_out,
    float* __restrict__ hbuf, unsigned* __restrict__ flags)
{
  __shared__ float sh_h[BB_ * DD_];          // 64 KB   [b][k]
  __shared__ float sh_x[BB_ * DD_];          // 64 KB   [b][k]
  __shared__ float sh_part[4 * 1040];        // [bb][col(16), pitch 65][lane]
  __shared__ float sh_yg[16][16];            // [b][localcol = gate*4+jj]
  __shared__ float sh_bias[16];

  const int tid  = threadIdx.x;
  const int wgid = blockIdx.x;       // owns gate columns wgid*4 + {0..3} per gate
  const int w    = tid >> 6;         // wave index: gate = w&3, batch-half = w>>2
  const int g    = w & 3;
  const int hf   = w >> 2;
  const int lane = tid & 63;

  // ---- weights -> registers. Thread rows: k = q*256 + lane*4 + c (q,c in 0..3).
  float4 wi_r[16], wh_r[16];
  {
    const float4* Wi4 = (const float4*)Wi;
    const float4* Wh4 = (const float4*)Wh;
    const int cbase = g * 256 + wgid;
#pragma unroll
    for (int q = 0; q < 4; ++q)
#pragma unroll
      for (int c = 0; c < 4; ++c) {
        const int row = q * 256 + lane * 4 + c;
        wi_r[q * 4 + c] = Wi4[(size_t)row * (GG_ / 4) + cbase];
        wh_r[q * 4 + c] = Wh4[(size_t)row * (GG_ / 4) + cbase];
      }
  }
  if (tid < 16)
    sh_bias[tid] = bias[(tid >> 2) * DD_ + wgid * 4 + (tid & 3)];

  // ---- preload h0 (carry[...,0], stride-2) and x_t=0 into LDS ----
  for (int f = tid; f < BB_ * DD_; f += NT)
    sh_h[f] = carry[(f >> 10) * (DD_ * 2) + (f & 1023) * 2];
  {
    const float4* xx = (const float4*)x;
#pragma unroll
    for (int r = 0; r < 8; ++r) {
      int f4 = r * NT + tid;
      int b = f4 >> 8, k4 = f4 & 255;
      ((float4*)sh_x)[f4] = xx[(size_t)b * (TT_ * DD_ / 4) + k4];
    }
  }

  // cell state lives in wave0 registers: lane = b*4 + jj
  float c_state = 0.f;
  if (tid < 64)
    c_state = carry[(tid >> 2) * (DD_ * 2) + (wgid * 4 + (tid & 3)) * 2 + 1];

  __syncthreads();

  // ---- prologue: xacc for t=0 (my wave's 8 bidx) from sh_x = x[0] ----
  // local m = bg*2 + p  ->  bidx = bg*4 + hf*2 + p
  float4 xacc[8];
#pragma unroll
  for (int m = 0; m < 8; ++m) {
    const int bidx = ((m >> 1) << 2) + (hf << 1) + (m & 1);
    const float* xbase = sh_x + bidx * DD_ + lane * 4;
    float4 a = make_float4(0.f, 0.f, 0.f, 0.f);
#pragma unroll
    for (int q = 0; q < 4; ++q) {
      float4 xv = *(const float4*)(xbase + q * 256);
      fma4(a, xv.x, wi_r[4*q+0]); fma4(a, xv.y, wi_r[4*q+1]);
      fma4(a, xv.z, wi_r[4*q+2]); fma4(a, xv.w, wi_r[4*q+3]);
    }
    xacc[m] = a;
  }

  float* hb0 = hbuf;
  float* hb1 = hbuf + BB_ * DD_;

  // per-thread producer flag for the gather: thread reads float cols 2tid,2tid+1
  // (both in col-quad tid>>1) of every row -> single producer WG tid>>1.
  const unsigned* const fp0 = &flags[tid >> 1];

  for (int t = 0; t < TT_; ++t) {
    // ======== h-part matvec (xacc pre-added): 4 batch-groups of 4 ========
    // wave w covers bb = hf*2 + {0,1} of each bg.
#pragma unroll 1
    for (int bg = 0; bg < 4; ++bg) {
#pragma unroll
      for (int p = 0; p < 2; ++p) {
        const int m    = bg * 2 + p;
        const int bb   = (hf << 1) + p;       // 0..3 within bg
        const int bidx = bg * 4 + bb;
        const float* hbase = sh_h + bidx * DD_ + lane * 4;
        float4 acc = xacc[m];
#pragma unroll
        for (int q = 0; q < 4; ++q) {
          float4 hv = *(const float4*)(hbase + q * 256);
          fma4(acc, hv.x, wh_r[4*q+0]);
          fma4(acc, hv.y, wh_r[4*q+1]);
          fma4(acc, hv.z, wh_r[4*q+2]);
          fma4(acc, hv.w, wh_r[4*q+3]);
        }
        float* pp = sh_part + bb * 1040 + (g * 4) * 65 + lane;
        pp[0]   = acc.x;
        pp[65]  = acc.y;
        pp[130] = acc.z;
        pp[195] = acc.w;
      }
      __syncthreads();
      if (tid < 256) {
        const int bb2 = tid >> 6, lc = (tid >> 2) & 15, sq = tid & 3;
        const float* pp = sh_part + bb2 * 1040 + lc * 65 + sq * 16;
        float s = 0.f;
#pragma unroll
        for (int i = 0; i < 16; ++i)
          s += pp[i];
        s += __shfl_xor(s, 1);
        s += __shfl_xor(s, 2);
        if (sq == 0)
          sh_yg[bg * 4 + bb2][lc] = s + sh_bias[lc];
      }
      __syncthreads();
    }

    // ======== pointwise: wave0, lane = b*4 + jj ========
    // Order: h-store -> drain -> flag -> NT out-store.
    float* hb_nxt = ((t + 1) & 1) ? hb1 : hb0;
    if (tid < 64) {
      const int cb = tid >> 2, jj = tid & 3;
      float gi = sigm_f(sh_yg[cb][jj]);
      float gf = sigm_f(sh_yg[cb][4 + jj]);
      float gg = tanh_f(sh_yg[cb][8 + jj]);
      float go = sigm_f(sh_yg[cb][12 + jj]);
      c_state = gf * c_state + gi * gg;
      float hn = go * tanh_f(c_state);
      __hip_atomic_store(&hb_nxt[cb * DD_ + wgid * 4 + jj], hn, __ATOMIC_RELAXED, SCOPE_AGENT);
      __builtin_amdgcn_sched_barrier(0);
      __builtin_amdgcn_s_waitcnt(0);          // wave-wide: drains all 64 lanes' h-stores
      __builtin_amdgcn_sched_barrier(0);
      if (tid == 0)
        __hip_atomic_store(&flags[wgid], (unsigned)(t + 1), __ATOMIC_RELAXED, SCOPE_AGENT);
      __builtin_amdgcn_sched_barrier(0);
      __builtin_nontemporal_store(hn, &out[(size_t)cb * (TT_ * DD_) + (size_t)t * DD_ + wgid * 4 + jj]);
      if (t == TT_ - 1) {
        carry_out[cb * (DD_ * 2) + (wgid * 4 + jj) * 2 + 0] = hn;
        carry_out[cb * (DD_ * 2) + (wgid * 4 + jj) * 2 + 1] = c_state;
      }
    }

    if (t + 1 < TT_) {
      // ======== prefetch x[t+1] into LDS (flag-propagation shadow) ========
      {
        const float4* xx = (const float4*)x;
#pragma unroll
        for (int r = 0; r < 8; ++r) {
          int f4 = r * NT + tid;
          int b = f4 >> 8, k4 = f4 & 255;
          ((float4*)sh_x)[f4] = xx[(size_t)b * (TT_ * DD_ / 4) + (size_t)(t + 1) * (DD_ / 4) + k4];
        }
      }
      __syncthreads();

      // ---- a1: x-part matvec for t+1, my bidx in batches 0..7 (m = 0..3) ----
#pragma unroll
      for (int m = 0; m < 4; ++m) {
        const int bidx = ((m >> 1) << 2) + (hf << 1) + (m & 1);   // in 0..7
        const float* xbase = sh_x + bidx * DD_ + lane * 4;
        float4 a = make_float4(0.f, 0.f, 0.f, 0.f);
#pragma unroll
        for (int q = 0; q < 4; ++q) {
          float4 xv = *(const float4*)(xbase + q * 256);
          fma4(a, xv.x, wi_r[4*q+0]); fma4(a, xv.y, wi_r[4*q+1]);
          fma4(a, xv.z, wi_r[4*q+2]); fma4(a, xv.w, wi_r[4*q+3]);
        }
        xacc[m] = a;
      }

      // ---- per-thread poll of the single producer flag ----
      {
        const unsigned tv = (unsigned)(t + 1);
        for (;;) {
          unsigned f0 = __hip_atomic_load(fp0, __ATOMIC_RELAXED, SCOPE_AGENT);
          if (f0 >= tv) break;
          __builtin_amdgcn_s_sleep(1);
        }
        __builtin_amdgcn_sched_barrier(0);
      }

      // ---- gather h(t+1) into registers (latency hidden by a2 below) ----
      unsigned long long hreg[16];
      {
        const unsigned long long* hb8 = (const unsigned long long*)hb_nxt;
#pragma unroll
        for (int r = 0; r < 16; ++r)
          hreg[r] = __hip_atomic_load(hb8 + r * NT + tid, __ATOMIC_RELAXED, SCOPE_AGENT);
      }
      __builtin_amdgcn_sched_barrier(0);   // pin gather issue above a2

      // ---- a2: x-part matvec for t+1, my bidx in batches 8..15 (m = 4..7) ----
#pragma unroll
      for (int m = 4; m < 8; ++m) {
        const int bidx = ((m >> 1) << 2) + (hf << 1) + (m & 1);   // in 8..15
        const float* xbase = sh_x + bidx * DD_ + lane * 4;
        float4 a = make_float4(0.f, 0.f, 0.f, 0.f);
#pragma unroll
        for (int q = 0; q < 4; ++q) {
          float4 xv = *(const float4*)(xbase + q * 256);
          fma4(a, xv.x, wi_r[4*q+0]); fma4(a, xv.y, wi_r[4*q+1]);
          fma4(a, xv.z, wi_r[4*q+2]); fma4(a, xv.w, wi_r[4*q+3]);
        }
        xacc[m] = a;
      }

      // ---- commit: drain gather, write h(t+1) to LDS ----
      asm volatile("s_waitcnt vmcnt(0)" ::: "memory");
      __builtin_amdgcn_sched_barrier(0);
      {
        unsigned long long* sh8 = (unsigned long long*)sh_h;
#pragma unroll
        for (int r = 0; r < 16; ++r)
          sh8[r * NT + tid] = hreg[r];
      }
      __syncthreads();
    }
  }
}

extern "C" void kernel_launch(void* const* d_in, const int* in_sizes, int n_in,
                              void* d_out, int out_size, void* d_ws, size_t ws_size,
                              hipStream_t stream) {
  const float* x     = (const float*)d_in[0];
  const float* carry = (const float*)d_in[1];
  const float* Wi    = (const float*)d_in[2];
  const float* Wh    = (const float*)d_in[3];
  const float* bias  = (const float*)d_in[4];
  float* out       = (float*)d_out;
  float* carry_out = out + (size_t)BB_ * TT_ * DD_;
  float* hbuf      = (float*)d_ws;   // 2 * B*D floats, written before read each step
  unsigned* flags  = (unsigned*)((char*)d_ws + (size_t)2 * BB_ * DD_ * sizeof(float));

  (void)hipMemsetAsync(flags, 0, NWG * sizeof(unsigned), stream);

  void* args[] = {(void*)&x, (void*)&carry, (void*)&Wi, (void*)&Wh, (void*)&bias,
                  (void*)&out, (void*)&carry_out, (void*)&hbuf, (void*)&flags};
  (void)hipLaunchCooperativeKernel((void*)lstm_persist, dim3(NWG), dim3(NT),
                                   args, 0, stream);
}

// Round 9
// 14708.080 us; speedup vs baseline: 2.5433x; 1.3055x over previous
//
#include <hip/hip_runtime.h>

// Problem constants (B,T,D fixed by setup_inputs)
#define BB_ 16
#define TT_ 2048
#define DD_ 1024
#define GG_ 4096   // 4*D
#define NWG 256
#define NT  512
#define SCOPE_AGENT __HIP_MEMORY_SCOPE_AGENT

// Persistent-LSTM, round 12: 8-wave + fused h-matvec + split-commit gather.
//  - Round-11 lesson: 2 waves/SIMD helped only ~0.5us -> remaining cost is the
//    step's INTERNAL serialization: 10 barriers/step, 4 serialized 256-thread
//    reduce rounds, gather tail exposed beyond a2.
//  - Changes (protocol + per-element arithmetic UNCHANGED):
//    1. Fused h-matvec: all 8 per-wave matvecs back-to-back; partials for
//       bb 4-15 staged in sh_x (dead during h-phase: its x[t+1] was consumed
//       into xacc in the previous tail; re-proven by barrier ordering).
//       ONE mega-reduce with all 512 threads (2 slots each, same arithmetic).
//       h-phase barriers: 8 -> 3.
//    2. Split-commit gather: tail commits rows 0-7 only; rows 8-15 commit at
//       the top of the next iteration after the bidx0-7 matvec block -> their
//       flight+commit hides under VALU. Compiler's per-value waitcnt handles
//       the partial vmcnt waits.
//    3. Barriers/step: 10 -> 5.
//  - Reuse-safety induction unchanged (round 9/11): ALL 16 gather loads are
//    consumed (so drained) by next-iter phase-2 commit, which precedes that
//    iter's flag publish; X's publish at t+2 follows X's poll of >= t+2.
//  - absmax must stay exactly 0.00390625.

__device__ __forceinline__ void fma4(float4& a, float s, const float4& w) {
  a.x = fmaf(s, w.x, a.x);
  a.y = fmaf(s, w.y, a.y);
  a.z = fmaf(s, w.z, a.z);
  a.w = fmaf(s, w.w, a.w);
}

__device__ __forceinline__ float sigm_f(float v) { return 1.f / (1.f + __expf(-v)); }
__device__ __forceinline__ float tanh_f(float v) { return 1.f - 2.f / (1.f + __expf(2.f * v)); }

__global__ __launch_bounds__(NT, 2) void lstm_persist(
    const float* __restrict__ x, const float* __restrict__ carry,
    const float* __restrict__ Wi, const float* __restrict__ Wh,
    const float* __restrict__ bias,
    float* __restrict__ out, float* __restrict__ carry_out,
    float* __restrict__ hbuf, unsigned* __restrict__ flags)
{
  __shared__ float sh_h[BB_ * DD_];          // 64 KB   [b][k]
  __shared__ float sh_x[BB_ * DD_];          // 64 KB   [b][k]; partials bb4-15 during h-phase
  __shared__ float sh_part[4 * 1040];        // partials bb0-3: [bb][col(16), pitch 65][lane]
  __shared__ float sh_yg[16][16];            // [b][localcol = gate*4+jj]
  __shared__ float sh_bias[16];

  const int tid  = threadIdx.x;
  const int wgid = blockIdx.x;       // owns gate columns wgid*4 + {0..3} per gate
  const int w    = tid >> 6;         // wave index: gate = w&3, batch-half = w>>2
  const int g    = w & 3;
  const int hf   = w >> 2;
  const int lane = tid & 63;

  // ---- weights -> registers. Thread rows: k = q*256 + lane*4 + c (q,c in 0..3).
  float4 wi_r[16], wh_r[16];
  {
    const float4* Wi4 = (const float4*)Wi;
    const float4* Wh4 = (const float4*)Wh;
    const int cbase = g * 256 + wgid;
#pragma unroll
    for (int q = 0; q < 4; ++q)
#pragma unroll
      for (int c = 0; c < 4; ++c) {
        const int row = q * 256 + lane * 4 + c;
        wi_r[q * 4 + c] = Wi4[(size_t)row * (GG_ / 4) + cbase];
        wh_r[q * 4 + c] = Wh4[(size_t)row * (GG_ / 4) + cbase];
      }
  }
  if (tid < 16)
    sh_bias[tid] = bias[(tid >> 2) * DD_ + wgid * 4 + (tid & 3)];

  // ---- preload h0 (carry[...,0], stride-2) and x_t=0 into LDS ----
  for (int f = tid; f < BB_ * DD_; f += NT)
    sh_h[f] = carry[(f >> 10) * (DD_ * 2) + (f & 1023) * 2];
  {
    const float4* xx = (const float4*)x;
#pragma unroll
    for (int r = 0; r < 8; ++r) {
      int f4 = r * NT + tid;
      int b = f4 >> 8, k4 = f4 & 255;
      ((float4*)sh_x)[f4] = xx[(size_t)b * (TT_ * DD_ / 4) + k4];
    }
  }

  // cell state lives in wave0 registers: lane = b*4 + jj
  float c_state = 0.f;
  if (tid < 64)
    c_state = carry[(tid >> 2) * (DD_ * 2) + (wgid * 4 + (tid & 3)) * 2 + 1];

  __syncthreads();

  // ---- prologue: xacc for t=0 (my wave's 8 bidx) from sh_x = x[0] ----
  // local m -> bidx = ((m>>1)<<2) + hf*2 + (m&1)
  float4 xacc[8];
#pragma unroll
  for (int m = 0; m < 8; ++m) {
    const int bidx = ((m >> 1) << 2) + (hf << 1) + (m & 1);
    const float* xbase = sh_x + bidx * DD_ + lane * 4;
    float4 a = make_float4(0.f, 0.f, 0.f, 0.f);
#pragma unroll
    for (int q = 0; q < 4; ++q) {
      float4 xv = *(const float4*)(xbase + q * 256);
      fma4(a, xv.x, wi_r[4*q+0]); fma4(a, xv.y, wi_r[4*q+1]);
      fma4(a, xv.z, wi_r[4*q+2]); fma4(a, xv.w, wi_r[4*q+3]);
    }
    xacc[m] = a;
  }

  float* hb0 = hbuf;
  float* hb1 = hbuf + BB_ * DD_;

  // per-thread producer flag: thread gathers float cols {2tid,2tid+1} -> WG tid>>1
  const unsigned* const fp0 = &flags[tid >> 1];

  unsigned long long hreg[16];
#pragma unroll
  for (int r = 0; r < 16; ++r) hreg[r] = 0ull;

  for (int t = 0; t < TT_; ++t) {
    // ======== phase 1: h-matvec partials, bidx 0-7 (rows 0-7 committed) ========
#pragma unroll
    for (int m = 0; m < 4; ++m) {
      const int bidx = ((m >> 1) << 2) + (hf << 1) + (m & 1);   // in 0..7
      const float* hbase = sh_h + bidx * DD_ + lane * 4;
      float4 acc = xacc[m];
#pragma unroll
      for (int q = 0; q < 4; ++q) {
        float4 hv = *(const float4*)(hbase + q * 256);
        fma4(acc, hv.x, wh_r[4*q+0]);
        fma4(acc, hv.y, wh_r[4*q+1]);
        fma4(acc, hv.z, wh_r[4*q+2]);
        fma4(acc, hv.w, wh_r[4*q+3]);
      }
      float* pp = (bidx < 4 ? sh_part + bidx * 1040 : sh_x + (bidx - 4) * 1040)
                  + (g * 4) * 65 + lane;
      pp[0]   = acc.x;
      pp[65]  = acc.y;
      pp[130] = acc.z;
      pp[195] = acc.w;
    }

    // ======== phase 2: commit gathered rows 8-15 (flight hidden by phase 1) ====
    if (t > 0) {
      unsigned long long* sh8 = (unsigned long long*)sh_h;
#pragma unroll
      for (int r = 8; r < 16; ++r)
        sh8[r * NT + tid] = hreg[r];
    }
    __syncthreads();

    // ======== phase 3: h-matvec partials, bidx 8-15 ========
#pragma unroll
    for (int m = 4; m < 8; ++m) {
      const int bidx = ((m >> 1) << 2) + (hf << 1) + (m & 1);   // in 8..15
      const float* hbase = sh_h + bidx * DD_ + lane * 4;
      float4 acc = xacc[m];
#pragma unroll
      for (int q = 0; q < 4; ++q) {
        float4 hv = *(const float4*)(hbase + q * 256);
        fma4(acc, hv.x, wh_r[4*q+0]);
        fma4(acc, hv.y, wh_r[4*q+1]);
        fma4(acc, hv.z, wh_r[4*q+2]);
        fma4(acc, hv.w, wh_r[4*q+3]);
      }
      float* pp = sh_x + (bidx - 4) * 1040 + (g * 4) * 65 + lane;
      pp[0]   = acc.x;
      pp[65]  = acc.y;
      pp[130] = acc.z;
      pp[195] = acc.w;
    }
    __syncthreads();

    // ======== phase 4: mega-reduce, all 512 threads, 2 slots each ========
#pragma unroll
    for (int pass = 0; pass < 2; ++pass) {
      const int bb = (tid >> 6) + pass * 8;   // 0..15
      const int lc = (tid >> 2) & 15, sq = tid & 3;
      const float* pp = (bb < 4 ? sh_part + bb * 1040 : sh_x + (bb - 4) * 1040)
                        + lc * 65 + sq * 16;
      float s = 0.f;
#pragma unroll
      for (int i = 0; i < 16; ++i)
        s += pp[i];
      s += __shfl_xor(s, 1);
      s += __shfl_xor(s, 2);
      if (sq == 0)
        sh_yg[bb][lc] = s + sh_bias[lc];
    }
    __syncthreads();

    // ======== phase 5: pointwise (wave0); publish h -> drain -> flag -> out ====
    float* hb_nxt = ((t + 1) & 1) ? hb1 : hb0;
    if (tid < 64) {
      const int cb = tid >> 2, jj = tid & 3;
      float gi = sigm_f(sh_yg[cb][jj]);
      float gf = sigm_f(sh_yg[cb][4 + jj]);
      float gg = tanh_f(sh_yg[cb][8 + jj]);
      float go = sigm_f(sh_yg[cb][12 + jj]);
      c_state = gf * c_state + gi * gg;
      float hn = go * tanh_f(c_state);
      __hip_atomic_store(&hb_nxt[cb * DD_ + wgid * 4 + jj], hn, __ATOMIC_RELAXED, SCOPE_AGENT);
      __builtin_amdgcn_sched_barrier(0);
      __builtin_amdgcn_s_waitcnt(0);          // wave-wide: drains all 64 lanes' h-stores
      __builtin_amdgcn_sched_barrier(0);
      if (tid == 0)
        __hip_atomic_store(&flags[wgid], (unsigned)(t + 1), __ATOMIC_RELAXED, SCOPE_AGENT);
      __builtin_amdgcn_sched_barrier(0);
      __builtin_nontemporal_store(hn, &out[(size_t)cb * (TT_ * DD_) + (size_t)t * DD_ + wgid * 4 + jj]);
      if (t == TT_ - 1) {
        carry_out[cb * (DD_ * 2) + (wgid * 4 + jj) * 2 + 0] = hn;
        carry_out[cb * (DD_ * 2) + (wgid * 4 + jj) * 2 + 1] = c_state;
      }
    }

    if (t + 1 < TT_) {
      // ======== phase 6: prefetch x[t+1] (waves 1-7 overlap wave0's publish) ====
      {
        const float4* xx = (const float4*)x;
#pragma unroll
        for (int r = 0; r < 8; ++r) {
          int f4 = r * NT + tid;
          int b = f4 >> 8, k4 = f4 & 255;
          ((float4*)sh_x)[f4] = xx[(size_t)b * (TT_ * DD_ / 4) + (size_t)(t + 1) * (DD_ / 4) + k4];
        }
      }
      __syncthreads();

      // ======== phase 7: a1 — x-matvec m 0..3 (flag-propagation shadow) ========
#pragma unroll
      for (int m = 0; m < 4; ++m) {
        const int bidx = ((m >> 1) << 2) + (hf << 1) + (m & 1);
        const float* xbase = sh_x + bidx * DD_ + lane * 4;
        float4 a = make_float4(0.f, 0.f, 0.f, 0.f);
#pragma unroll
        for (int q = 0; q < 4; ++q) {
          float4 xv = *(const float4*)(xbase + q * 256);
          fma4(a, xv.x, wi_r[4*q+0]); fma4(a, xv.y, wi_r[4*q+1]);
          fma4(a, xv.z, wi_r[4*q+2]); fma4(a, xv.w, wi_r[4*q+3]);
        }
        xacc[m] = a;
      }

      // ======== phase 8: poll producer flag; gather 16; a2 in gather shadow ====
      {
        const unsigned tv = (unsigned)(t + 1);
        for (;;) {
          unsigned f0 = __hip_atomic_load(fp0, __ATOMIC_RELAXED, SCOPE_AGENT);
          if (f0 >= tv) break;
          __builtin_amdgcn_s_sleep(1);
        }
        __builtin_amdgcn_sched_barrier(0);
      }
      {
        const unsigned long long* hb8 = (const unsigned long long*)hb_nxt;
#pragma unroll
        for (int r = 0; r < 16; ++r)
          hreg[r] = __hip_atomic_load(hb8 + r * NT + tid, __ATOMIC_RELAXED, SCOPE_AGENT);
      }
      __builtin_amdgcn_sched_barrier(0);   // pin gather issue above a2

#pragma unroll
      for (int m = 4; m < 8; ++m) {
        const int bidx = ((m >> 1) << 2) + (hf << 1) + (m & 1);
        const float* xbase = sh_x + bidx * DD_ + lane * 4;
        float4 a = make_float4(0.f, 0.f, 0.f, 0.f);
#pragma unroll
        for (int q = 0; q < 4; ++q) {
          float4 xv = *(const float4*)(xbase + q * 256);
          fma4(a, xv.x, wi_r[4*q+0]); fma4(a, xv.y, wi_r[4*q+1]);
          fma4(a, xv.z, wi_r[4*q+2]); fma4(a, xv.w, wi_r[4*q+3]);
        }
        xacc[m] = a;
      }

      // ======== phase 9: commit rows 0-7 (compiler waits vmcnt for hreg[0..7]);
      //          rows 8-15 stay in flight/regs until next iteration's phase 2 ====
      {
        unsigned long long* sh8 = (unsigned long long*)sh_h;
#pragma unroll
        for (int r = 0; r < 8; ++r)
          sh8[r * NT + tid] = hreg[r];
      }
      __syncthreads();
    }
  }
}

extern "C" void kernel_launch(void* const* d_in, const int* in_sizes, int n_in,
                              void* d_out, int out_size, void* d_ws, size_t ws_size,
                              hipStream_t stream) {
  const float* x     = (const float*)d_in[0];
  const float* carry = (const float*)d_in[1];
  const float* Wi    = (const float*)d_in[2];
  const float* Wh    = (const float*)d_in[3];
  const float* bias  = (const float*)d_in[4];
  float* out       = (float*)d_out;
  float* carry_out = out + (size_t)BB_ * TT_ * DD_;
  float* hbuf      = (float*)d_ws;   // 2 * B*D floats, written before read each step
  unsigned* flags  = (unsigned*)((char*)d_ws + (size_t)2 * BB_ * DD_ * sizeof(float));

  (void)hipMemsetAsync(flags, 0, NWG * sizeof(unsigned), stream);

  void* args[] = {(void*)&x, (void*)&carry, (void*)&Wi, (void*)&Wh, (void*)&bias,
                  (void*)&out, (void*)&carry_out, (void*)&hbuf, (void*)&flags};
  (void)hipLaunchCooperativeKernel((void*)lstm_persist, dim3(NWG), dim3(NT),
                                   args, 0, stream);
}